// Round 2
// baseline (1079.022 us; speedup 1.0000x reference)
//
#include <hip/hip_runtime.h>
#include <cstdint>
#include <cstddef>

#define N_TOK 8192
#define DIM   1024
#define HID   4096
#define DOUT  1024
#define NEXP  8
#define BM 256
#define BN 256
#define BK 32

typedef short  s16x8 __attribute__((ext_vector_type(8)));
typedef __bf16 b16x8 __attribute__((ext_vector_type(8)));
typedef float  f32x4 __attribute__((ext_vector_type(4)));

__device__ __forceinline__ unsigned short f2bf(float f) {
  unsigned u = __float_as_uint(f);
  u += 0x7fffu + ((u >> 16) & 1u);
  return (unsigned short)(u >> 16);
}

__device__ __forceinline__ float gelu_f(float v) {
  return 0.5f * v * (1.0f + erff(v * 0.70710678118654752440f));
}

// async global->LDS, 16B per lane. LDS dest wave-uniform base; HW writes
// lane i at base + i*16. Global src is per-lane (enables source pre-swizzle).
__device__ __forceinline__ void gl_lds16(const void* g, void* l) {
  auto gp = (__attribute__((address_space(1))) void*)(reinterpret_cast<uintptr_t>(g));
  auto lp = (__attribute__((address_space(3))) void*)(reinterpret_cast<uintptr_t>(l));
  __builtin_amdgcn_global_load_lds(gp, lp, 16, 0, 0);
}

// ---------------- small kernels ----------------

__global__ void init_kernel(int* counts) {
  if (threadIdx.x < NEXP) counts[threadIdx.x] = 0;
}

__global__ void cast_x_kernel(const float* __restrict__ src,
                              unsigned short* __restrict__ dst) {
  int i = blockIdx.x * 256 + threadIdx.x;
  float4 v = reinterpret_cast<const float4*>(src)[i];
  ushort4 o;
  o.x = f2bf(v.x); o.y = f2bf(v.y); o.z = f2bf(v.z); o.w = f2bf(v.w);
  reinterpret_cast<ushort4*>(dst)[i] = o;
}

// src [R][C] f32 (batched by blockIdx.z) -> dst [C][R] bf16
__global__ void transpose_cast_kernel(const float* __restrict__ src,
                                      unsigned short* __restrict__ dst,
                                      int R, int C) {
  __shared__ float tile[32][33];
  size_t base = (size_t)blockIdx.z * (size_t)R * (size_t)C;
  src += base; dst += base;
  int c0 = blockIdx.x * 32, r0 = blockIdx.y * 32;
  int tx = threadIdx.x, ty = threadIdx.y;  // 32 x 8
#pragma unroll
  for (int i = 0; i < 4; ++i)
    tile[ty + 8 * i][tx] = src[(size_t)(r0 + ty + 8 * i) * C + (c0 + tx)];
  __syncthreads();
#pragma unroll
  for (int i = 0; i < 4; ++i)
    dst[(size_t)(c0 + ty + 8 * i) * R + (r0 + tx)] = f2bf(tile[tx][ty + 8 * i]);
}

// one wave per token: f32 gate logits, top-2, renormalized weights
__global__ void gate_kernel(const float* __restrict__ x,
                            const float* __restrict__ gw,
                            int* __restrict__ topk_e,
                            float* __restrict__ topk_w,
                            int* __restrict__ counts) {
  int w = threadIdx.x >> 6, lane = threadIdx.x & 63;
  int t = blockIdx.x * 4 + w;
  const float* xr = x + (size_t)t * DIM;
  float acc[8];
#pragma unroll
  for (int e = 0; e < 8; ++e) acc[e] = 0.f;
  for (int i = 0; i < DIM / 64; ++i) {
    int d = lane + (i << 6);
    float xv = xr[d];
    float4 g0 = *reinterpret_cast<const float4*>(gw + (size_t)d * 8);
    float4 g1 = *reinterpret_cast<const float4*>(gw + (size_t)d * 8 + 4);
    acc[0] += xv * g0.x; acc[1] += xv * g0.y; acc[2] += xv * g0.z; acc[3] += xv * g0.w;
    acc[4] += xv * g1.x; acc[5] += xv * g1.y; acc[6] += xv * g1.z; acc[7] += xv * g1.w;
  }
#pragma unroll
  for (int o = 32; o; o >>= 1)
#pragma unroll
    for (int e = 0; e < 8; ++e) acc[e] += __shfl_down(acc[e], o);
  if (lane == 0) {
    int e0 = 0;
#pragma unroll
    for (int e = 1; e < 8; ++e) if (acc[e] > acc[e0]) e0 = e;
    int e1 = -1;
#pragma unroll
    for (int e = 0; e < 8; ++e) {
      if (e == e0) continue;
      if (e1 < 0 || acc[e] > acc[e1]) e1 = e;
    }
    float w0 = 1.0f / (1.0f + expf(acc[e1] - acc[e0]));  // == p0/(p0+p1)
    topk_e[t * 2 + 0] = e0;
    topk_e[t * 2 + 1] = e1;
    topk_w[t * 2 + 0] = w0;
    topk_w[t * 2 + 1] = 1.0f - w0;
    atomicAdd(&counts[e0], 1);
    atomicAdd(&counts[e1], 1);
  }
}

__global__ void offsets_kernel(const int* __restrict__ counts,
                               int* __restrict__ offsets,
                               int* __restrict__ cursor) {
  if (threadIdx.x == 0) {
    int o = 0;
    for (int e = 0; e < NEXP; ++e) {
      offsets[e] = o; cursor[e] = o; o += counts[e];
    }
    offsets[NEXP] = o;
  }
}

__global__ void scatter_kernel(const int* __restrict__ topk_e,
                               int* __restrict__ cursor,
                               int* __restrict__ rowmap,
                               int* __restrict__ inv) {
  int t = blockIdx.x * 256 + threadIdx.x;
#pragma unroll
  for (int s = 0; s < 2; ++s) {
    int e = topk_e[t * 2 + s];
    int p = atomicAdd(&cursor[e], 1);
    rowmap[p] = t * 2 + s;
    inv[t * 2 + s] = p;
  }
}

// ---------------- deep-pipelined MFMA GEMM (256x256 tile, BK=32) ----------------
// C[M x Ncols] = A[. x K] * Bt[Ncols x K], both operands K-contiguous rows.
// 8 waves (2M x 4N), per-wave output 128x64, acc[8][4] f32x4.
// 4-buffer LDS ring (128 KiB), staging 3 K-tiles ahead, counted vmcnt(8),
// single raw s_barrier per K-tile, setprio around the MFMA cluster.
// LDS tiles are XOR-swizzled (chunk ^= (row>>1)&3) via pre-swizzled global
// source addresses (gl_lds writes linearly) + swizzled ds_read addresses.
// MODE 0: expert GEMM1, gathered A rows, epi: h = gelu(acc+b1) -> bf16
// MODE 1: expert GEMM2, compact A (h), epi: fOut[slot] = w*(acc+b2)  (f32)
// MODE 2: shared GEMM, dense, epi: fOut = 0.5*gelu(acc+b)            (f32)
template <int MODE>
__global__ __launch_bounds__(512, 2) void gemm_mfma(
    const unsigned short* __restrict__ A,
    const unsigned short* __restrict__ Ball,
    const float* __restrict__ biasAll,
    unsigned short* __restrict__ hOut,
    float* __restrict__ fOut,
    const int* __restrict__ rowmap,
    const int* __restrict__ offsets,
    const float* __restrict__ topkw,
    int K, int Ncols, int M2, int MT, int NT) {
  // T1: XCD-chunked bijective swizzle (grid sizes are multiples of 8).
  // mt-fastest within a chunk -> blocks sharing a B-panel are XCD-local.
  int nwg = gridDim.x;
  int bid = blockIdx.x;
  int lg = (bid & 7) * (nwg >> 3) + (bid >> 3);

  int e, mt, nt, rowBase, cnt;
  if (MODE == 2) {
    e = 0; rowBase = 0; cnt = M2;
    nt = lg / MT; mt = lg % MT;
  } else {
    int per = MT * NT;
    e = lg / per;
    int rem = lg % per;
    nt = rem / MT; mt = rem % MT;
    rowBase = offsets[e];
    cnt = offsets[e + 1] - rowBase;
    if (mt * BM >= cnt) return;
  }
  const unsigned short* B = Ball + (size_t)e * Ncols * K;
  const float* bias = biasAll + (size_t)e * Ncols;

  int t = threadIdx.x;
  int w = t >> 6, lane = t & 63;
  int wm = w >> 2, wn = w & 3;
  int fr = lane & 15, fg = lane >> 4;

  __shared__ __attribute__((aligned(16))) unsigned short lds[4][16384];

  // ---- staging geometry: thread t covers tile-row r*128+(t>>2), 16B chunk.
  // Inverse-swizzled global chunk so linear gl_lds writes land swizzled.
  int cg = (t & 3) ^ ((t >> 3) & 3);
  const unsigned short* aptr[2];
  const unsigned short* bptr[2];
#pragma unroll
  for (int r = 0; r < 2; ++r) {
    int rr = r * 128 + (t >> 2);
    int gr = mt * BM + rr;
    size_t arow;
    if (MODE == 0) {
      int rc = gr < cnt ? gr : cnt - 1;
      arow = (size_t)(rowmap[rowBase + rc] >> 1);
    } else if (MODE == 1) {
      int rc = gr < cnt ? gr : cnt - 1;
      arow = (size_t)(rowBase + rc);
    } else {
      arow = (size_t)gr;
    }
    aptr[r] = A + arow * (size_t)K + cg * 8;
    bptr[r] = B + (size_t)(nt * BN + rr) * K + cg * 8;
  }

  auto stage = [&](int b, int kt) {
    int ko = kt * BK;
    unsigned short* p = &lds[b][w << 9];  // wave-uniform LDS base
    gl_lds16(aptr[0] + ko, p);
    gl_lds16(aptr[1] + ko, p + 4096);
    gl_lds16(bptr[0] + ko, p + 8192);
    gl_lds16(bptr[1] + ko, p + 12288);
  };

  // ---- fragment read offsets (elements), swizzle folded per-thread:
  // (row>>1)&3 == (fr>>1)&3 for all fragments since frag row bases are x16.
  int sw = fg ^ ((fr >> 1) & 3);
  int a_off = (wm * 128 + fr) * 32 + sw * 8;
  int b_off = 8192 + (wn * 64 + fr) * 32 + sw * 8;

  f32x4 acc[8][4] = {};
  s16x8 af[8];
  s16x8 bf[4];

#define LOADFRAGS(BUF)                                                         \
  {                                                                            \
    const unsigned short* _p = &lds[BUF][0];                                   \
    _Pragma("unroll") for (int m = 0; m < 8; ++m)                              \
        af[m] = *reinterpret_cast<const s16x8*>(_p + a_off + m * 512);         \
    _Pragma("unroll") for (int n = 0; n < 4; ++n)                              \
        bf[n] = *reinterpret_cast<const s16x8*>(_p + b_off + n * 512);         \
  }

#define DOMFMA()                                                               \
  {                                                                            \
    __builtin_amdgcn_s_setprio(1);                                             \
    _Pragma("unroll") for (int m = 0; m < 8; ++m)                              \
        _Pragma("unroll") for (int n = 0; n < 4; ++n)                          \
            acc[m][n] = __builtin_amdgcn_mfma_f32_16x16x32_bf16(               \
                __builtin_bit_cast(b16x8, af[m]),                              \
                __builtin_bit_cast(b16x8, bf[n]), acc[m][n], 0, 0, 0);         \
    __builtin_amdgcn_s_setprio(0);                                             \
  }

  int KT = K / BK;  // 32 or 128; >= 4 always

  // prologue: 3 tiles in flight; wait tile 0 (8 = 2 tiles outstanding)
  stage(0, 0); stage(1, 1); stage(2, 2);
  asm volatile("s_waitcnt vmcnt(8)" ::: "memory");
  asm volatile("s_barrier" ::: "memory");

  // invariant at iteration top: tile kt landed+visible, 8 loads outstanding.
  for (int kt = 0; kt < KT - 3; ++kt) {
    LOADFRAGS(kt & 3);
    stage((kt + 3) & 3, kt + 3);  // overwrites buf[(kt-1)&3]: reads done @B(kt-1)
    // tile kt+1 landed; my frag reads complete (so next stage may overwrite)
    asm volatile("s_waitcnt vmcnt(8) lgkmcnt(0)" ::: "memory");
    __builtin_amdgcn_sched_barrier(0);
    asm volatile("s_barrier" ::: "memory");
    __builtin_amdgcn_sched_barrier(0);
    DOMFMA();
  }
  // tail: 3 tiles, no more staging
  LOADFRAGS((KT - 3) & 3);
  asm volatile("s_waitcnt vmcnt(4) lgkmcnt(0)" ::: "memory");
  asm volatile("s_barrier" ::: "memory");
  DOMFMA();
  LOADFRAGS((KT - 2) & 3);
  asm volatile("s_waitcnt vmcnt(0) lgkmcnt(0)" ::: "memory");
  asm volatile("s_barrier" ::: "memory");
  DOMFMA();
  LOADFRAGS((KT - 1) & 3);
  asm volatile("s_waitcnt lgkmcnt(0)" ::: "memory");
  __builtin_amdgcn_sched_barrier(0);
  DOMFMA();
#undef LOADFRAGS
#undef DOMFMA

  // ---- epilogue: C/D layout col=lane&15, row=(lane>>4)*4+q
  if (MODE == 0) {
#pragma unroll
    for (int n = 0; n < 4; ++n) {
      int col = nt * BN + wn * 64 + n * 16 + fr;
      float bc = bias[col];
#pragma unroll
      for (int m = 0; m < 8; ++m) {
#pragma unroll
        for (int q = 0; q < 4; ++q) {
          int r = mt * BM + wm * 128 + m * 16 + fg * 4 + q;
          if (r < cnt)
            hOut[(size_t)(rowBase + r) * (size_t)Ncols + col] =
                f2bf(gelu_f(acc[m][n][q] + bc));
        }
      }
    }
  } else if (MODE == 1) {
    int cols[4];
    float bc[4];
#pragma unroll
    for (int n = 0; n < 4; ++n) {
      cols[n] = nt * BN + wn * 64 + n * 16 + fr;
      bc[n] = bias[cols[n]];
    }
#pragma unroll
    for (int m = 0; m < 8; ++m) {
#pragma unroll
      for (int q = 0; q < 4; ++q) {
        int r = mt * BM + wm * 128 + m * 16 + fg * 4 + q;
        if (r < cnt) {
          float wgt = topkw[rowmap[rowBase + r]];
          float* orow = fOut + (size_t)(rowBase + r) * (size_t)Ncols;
#pragma unroll
          for (int n = 0; n < 4; ++n)
            orow[cols[n]] = wgt * (acc[m][n][q] + bc[n]);
        }
      }
    }
  } else {
#pragma unroll
    for (int n = 0; n < 4; ++n) {
      int col = nt * BN + wn * 64 + n * 16 + fr;
      float bc = bias[col];
#pragma unroll
      for (int m = 0; m < 8; ++m) {
#pragma unroll
        for (int q = 0; q < 4; ++q) {
          int r = mt * BM + wm * 128 + m * 16 + fg * 4 + q;
          fOut[(size_t)r * (size_t)Ncols + col] = 0.5f * gelu_f(acc[m][n][q] + bc);
        }
      }
    }
  }
}

// ---------------- LayerNorm (gathers shared + 2 expert slots) ----------------
__global__ void ln_kernel(const float* __restrict__ sh,
                          const float* __restrict__ acc2,
                          const int* __restrict__ inv,
                          const float* __restrict__ gamma,
                          const float* __restrict__ beta,
                          float* __restrict__ out) {
  int t = blockIdx.x, tid = threadIdx.x;
  int i0 = inv[t * 2 + 0], i1 = inv[t * 2 + 1];
  float4 a  = reinterpret_cast<const float4*>(sh   + (size_t)t  * DOUT)[tid];
  float4 c0 = reinterpret_cast<const float4*>(acc2 + (size_t)i0 * DOUT)[tid];
  float4 c1 = reinterpret_cast<const float4*>(acc2 + (size_t)i1 * DOUT)[tid];
  float4 v;
  v.x = a.x + c0.x + c1.x;
  v.y = a.y + c0.y + c1.y;
  v.z = a.z + c0.z + c1.z;
  v.w = a.w + c0.w + c1.w;
  float s = v.x + v.y + v.z + v.w;
  float q = v.x * v.x + v.y * v.y + v.z * v.z + v.w * v.w;
#pragma unroll
  for (int o = 32; o; o >>= 1) {
    s += __shfl_down(s, o);
    q += __shfl_down(q, o);
  }
  __shared__ float ss[4], sq[4];
  int w = tid >> 6, lane = tid & 63;
  if (lane == 0) { ss[w] = s; sq[w] = q; }
  __syncthreads();
  float S = ss[0] + ss[1] + ss[2] + ss[3];
  float Q = sq[0] + sq[1] + sq[2] + sq[3];
  float mean = S * (1.0f / DOUT);
  float var = Q * (1.0f / DOUT) - mean * mean;
  float inv_std = rsqrtf(var + 1e-5f);
  float4 g = reinterpret_cast<const float4*>(gamma)[tid];
  float4 b = reinterpret_cast<const float4*>(beta)[tid];
  float4 o;
  o.x = (v.x - mean) * inv_std * g.x + b.x;
  o.y = (v.y - mean) * inv_std * g.y + b.y;
  o.z = (v.z - mean) * inv_std * g.z + b.z;
  o.w = (v.w - mean) * inv_std * g.w + b.w;
  reinterpret_cast<float4*>(out + (size_t)t * DOUT)[tid] = o;
}

// ---------------- host ----------------
extern "C" void kernel_launch(void* const* d_in, const int* in_sizes, int n_in,
                              void* d_out, int out_size, void* d_ws, size_t ws_size,
                              hipStream_t stream) {
  const float* x       = (const float*)d_in[0];
  const float* W1      = (const float*)d_in[1];
  const float* b1      = (const float*)d_in[2];
  const float* W2      = (const float*)d_in[3];
  const float* b2      = (const float*)d_in[4];
  const float* gateW   = (const float*)d_in[5];
  const float* sharedW = (const float*)d_in[6];
  const float* sharedB = (const float*)d_in[7];
  const float* gamma   = (const float*)d_in[8];
  const float* beta    = (const float*)d_in[9];
  float* out = (float*)d_out;

  char* ws = (char*)d_ws;
  size_t off = 0;
  auto alloc = [&](size_t bytes) -> void* {
    void* p = ws + off;
    off += (bytes + 255) & ~(size_t)255;
    return p;
  };
  int*   counts = (int*)alloc(NEXP * 4);
  int*   offs   = (int*)alloc((NEXP + 1) * 4);
  int*   cursor = (int*)alloc(NEXP * 4);
  int*   topk_e = (int*)alloc((size_t)N_TOK * 2 * 4);
  float* topk_w = (float*)alloc((size_t)N_TOK * 2 * 4);
  int*   rowmap = (int*)alloc((size_t)N_TOK * 2 * 4);
  int*   inv    = (int*)alloc((size_t)N_TOK * 2 * 4);
  unsigned short* xbf  = (unsigned short*)alloc((size_t)N_TOK * DIM * 2);
  unsigned short* W1t  = (unsigned short*)alloc((size_t)NEXP * HID * DIM * 2);
  unsigned short* W2t  = (unsigned short*)alloc((size_t)NEXP * DOUT * HID * 2);
  unsigned short* sWt  = (unsigned short*)alloc((size_t)DOUT * DIM * 2);
  unsigned short* hbuf = (unsigned short*)alloc((size_t)N_TOK * 2 * HID * 2);
  float* acc2 = (float*)alloc((size_t)N_TOK * 2 * DOUT * 4);
  // shbuf aliases W1t's storage (W1t is dead after GEMM1; shared GEMM runs after)
  float* shbuf = (float*)W1t;
  if (off > ws_size) return;  // workspace too small -> fail validation loudly

  init_kernel<<<1, 64, 0, stream>>>(counts);
  cast_x_kernel<<<N_TOK * DIM / 1024, 256, 0, stream>>>(x, xbf);
  transpose_cast_kernel<<<dim3(HID / 32, DIM / 32, NEXP), dim3(32, 8), 0, stream>>>(W1, W1t, DIM, HID);
  transpose_cast_kernel<<<dim3(DOUT / 32, HID / 32, NEXP), dim3(32, 8), 0, stream>>>(W2, W2t, HID, DOUT);
  transpose_cast_kernel<<<dim3(DOUT / 32, DIM / 32, 1), dim3(32, 8), 0, stream>>>(sharedW, sWt, DIM, DOUT);
  gate_kernel<<<N_TOK / 4, 256, 0, stream>>>(x, gateW, topk_e, topk_w, counts);
  offsets_kernel<<<1, 64, 0, stream>>>(counts, offs, cursor);
  scatter_kernel<<<N_TOK / 256, 256, 0, stream>>>(topk_e, cursor, rowmap, inv);

  // GEMM1: h = gelu(x @ W1 + b1); MT=16 covers cnt<=4096/expert (E[cnt]=2048)
  gemm_mfma<0><<<NEXP * 16 * (HID / BN), 512, 0, stream>>>(
      xbf, W1t, b1, hbuf, nullptr, rowmap, offs, topk_w, DIM, HID, 0, 16, HID / BN);
  // shared: shbuf = 0.5*gelu(x @ sharedW + sb)
  gemm_mfma<2><<<(N_TOK / BM) * (DOUT / BN), 512, 0, stream>>>(
      xbf, sWt, sharedB, nullptr, shbuf, nullptr, nullptr, nullptr, DIM, DOUT,
      N_TOK, N_TOK / BM, DOUT / BN);
  // GEMM2: acc2[slot] = w * (h @ W2 + b2)   (compact, no atomics)
  gemm_mfma<1><<<NEXP * 16 * (DOUT / BN), 512, 0, stream>>>(
      hbuf, W2t, b2, nullptr, acc2, rowmap, offs, topk_w, HID, DOUT, 0, 16, DOUT / BN);
  // LayerNorm(shared + slot0 + slot1) -> out
  ln_kernel<<<N_TOK, 256, 0, stream>>>(shbuf, acc2, inv, gamma, beta, out);
}